// Round 8
// baseline (464.869 us; speedup 1.0000x reference)
//
#include <hip/hip_runtime.h>
#include <hip/hip_bf16.h>
#include <hip/hip_cooperative_groups.h>

namespace cg = cooperative_groups;

typedef __bf16 bf16x8 __attribute__((ext_vector_type(8)));
typedef __bf16 bf16x4 __attribute__((ext_vector_type(4)));
typedef float f32x4 __attribute__((ext_vector_type(4)));

// scale = d^-0.5 * log2(e): attention runs in log2 domain (exp2, no max needed:
// GroupNorm'd activations x 0.02-scale weights give |scores| < ~0.5 log2 units)
#define QSCALE (0.17677669529663689f * 1.44269504088896340736f)

__device__ __forceinline__ f32x4 mfma_16x16x32(bf16x8 a, bf16x8 b, f32x4 c) {
  return __builtin_amdgcn_mfma_f32_16x16x32_bf16(a, b, c, 0, 0, 0);
}

// Single cooperative kernel: A) GN stats + weight pack, B) GN-apply + QKV,
// C) flash attention (64 q/wave, LDS-pipelined K/V), D) combine + out-proj.
// grid 512 x 256: 2 blocks/CU co-resident (LDS 14.6KB, VGPR<=256).
__global__ __launch_bounds__(256, 2) void mega_kernel(
    const float* __restrict__ x, const float* __restrict__ nw,
    const float* __restrict__ nb, const float* __restrict__ pw,
    const float* __restrict__ pb, const float* __restrict__ ow,
    const float* __restrict__ ob, float* __restrict__ out,
    float* __restrict__ stats, __bf16* __restrict__ Qb,
    __bf16* __restrict__ Kp, __bf16* __restrict__ Vb,
    __bf16* __restrict__ Op, float* __restrict__ Lp,
    __bf16* __restrict__ Wp, __bf16* __restrict__ Wq) {
  cg::grid_group grid = cg::this_grid();
  __shared__ __align__(16) char smraw[14592];
  int blk = blockIdx.x, tid = threadIdx.x;
  int wave = tid >> 6, lane = tid & 63;
  int g = lane >> 4, r = lane & 15;

  // ---------------- Phase A: GroupNorm stats + weight pre-pack -------------
  if (blk < 64) {
    int bg = blk;
    const f32x4* base = (const f32x4*)(x + (size_t)bg * 16384);
    float s = 0.f, ss = 0.f;
    for (int i = tid; i < 4096; i += 256) {
      f32x4 v = base[i];
      s += v[0] + v[1] + v[2] + v[3];
      ss += v[0]*v[0] + v[1]*v[1] + v[2]*v[2] + v[3]*v[3];
    }
    #pragma unroll
    for (int off = 32; off; off >>= 1) {
      s += __shfl_down(s, off);
      ss += __shfl_down(ss, off);
    }
    float* rs = (float*)smraw;
    float* rss = rs + 4;
    if ((tid & 63) == 0) { rs[wave] = s; rss[wave] = ss; }
    __syncthreads();
    if (tid == 0) {
      float S = rs[0] + rs[1] + rs[2] + rs[3];
      float SS = rss[0] + rss[1] + rss[2] + rss[3];
      float mean = S * (1.f / 16384.f);
      float var = SS * (1.f / 16384.f) - mean * mean;
      stats[bg * 2] = mean;
      stats[bg * 2 + 1] = rsqrtf(var + 1e-5f);
    }
  } else if (blk < 96) {
    int idx = (blk - 64) * 256 + tid;  // 0..8191
    const float* src;
    __bf16* dst;
    if (idx < 6144) {
      int ln = idx & 63, ks = (idx >> 6) & 3;
      int rest = idx >> 8;  // 0..23
      int ot = rest % 6, hh = rest / 6;
      src = pw + (size_t)(hh * 96 + ot * 16 + (ln & 15)) * 128 + ks * 32 +
            8 * (ln >> 4);
      dst = Wp + (size_t)idx * 8;
    } else {
      int j = idx - 6144;  // 0..2047
      int ln = j & 63, ks = (j >> 6) & 3;
      int rest = j >> 8;  // 0..7
      int ot = rest & 1, wv = rest >> 1;
      src = ow + (size_t)(wv * 32 + ot * 16 + (ln & 15)) * 128 + ks * 32 +
            8 * (ln >> 4);
      dst = Wq + (size_t)j * 8;
    }
    f32x4 a = *(const f32x4*)src;
    f32x4 b2 = *(const f32x4*)(src + 4);
    bf16x8 w;
    #pragma unroll
    for (int i = 0; i < 4; ++i) { w[i] = (__bf16)a[i]; w[4 + i] = (__bf16)b2[i]; }
    *(bf16x8*)dst = w;
  }
  __threadfence();
  grid.sync();

  // ---------------- Phase B: GroupNorm apply + QKV projection --------------
  {
    __bf16* ht = (__bf16*)smraw;  // XOR-swizzled [token16][c128]
    int chunk = blk & 255;
    int b = blk >> 8;
    int n0 = chunk * 16;
    {
      int c = tid >> 1, hf = tid & 1;
      const float* xs = x + ((size_t)b * 128 + c) * 4096 + n0 + hf * 8;
      f32x4 x0 = *(const f32x4*)xs;
      f32x4 x1 = *(const f32x4*)(xs + 4);
      float mean = stats[(b * 32 + (c >> 2)) * 2];
      float rstd = stats[(b * 32 + (c >> 2)) * 2 + 1];
      float wsc = nw[c], bsc = nb[c];
      #pragma unroll
      for (int j = 0; j < 8; ++j) {
        float v = (j < 4) ? x0[j] : x1[j - 4];
        float hv = (v - mean) * rstd * wsc + bsc;
        int tok = hf * 8 + j;
        int byte = (tok * 256 + c * 2) ^ ((tok & 7) << 4);
        *(__bf16*)((char*)ht + byte) = (__bf16)hv;
      }
    }
    int hh = wave;
    bf16x8 wf[6][4];
    const bf16x8* wpp = (const bf16x8*)Wp;
    #pragma unroll
    for (int ot = 0; ot < 6; ++ot)
      #pragma unroll
      for (int ks = 0; ks < 4; ++ks)
        wf[ot][ks] = wpp[((hh * 6 + ot) * 4 + ks) * 64 + lane];
    __syncthreads();
    bf16x8 bfr[4];
    #pragma unroll
    for (int ks = 0; ks < 4; ++ks) {
      int byte = (r * 256 + (ks * 32 + 8 * g) * 2) ^ ((r & 7) << 4);
      bfr[ks] = *(const bf16x8*)((char*)ht + byte);
    }
    f32x4 acc[6];
    #pragma unroll
    for (int ot = 0; ot < 6; ++ot) acc[ot] = (f32x4){0.f, 0.f, 0.f, 0.f};
    #pragma unroll
    for (int ks = 0; ks < 4; ++ks)
      #pragma unroll
      for (int ot = 0; ot < 6; ++ot)
        acc[ot] = mfma_16x16x32(wf[ot][ks], bfr[ks], acc[ot]);
    int bh = b * 4 + hh;
    int n = n0 + r;
    #pragma unroll
    for (int ot = 0; ot < 6; ++ot) {
      int o_lo = ot * 16 + 4 * g;
      f32x4 bias = *(const f32x4*)(pb + hh * 96 + o_lo);
      f32x4 v = acc[ot];
      if (ot < 2) {
        bf16x4 qv;
        #pragma unroll
        for (int i = 0; i < 4; ++i) qv[i] = (__bf16)((v[i] + bias[i]) * QSCALE);
        *(bf16x4*)(Qb + ((size_t)bh * 4096 + n) * 32 + o_lo) = qv;
      } else if (ot < 4) {
        bf16x4 kv;
        #pragma unroll
        for (int i = 0; i < 4; ++i) kv[i] = (__bf16)(v[i] + bias[i]);
        size_t koff = ((size_t)(bh * 128 + (n >> 5))) * 1024 +
                      (size_t)((n >> 4) & 1) * 512 +
                      ((n & 15) + 16 * ((ot - 2) * 2 + (g >> 1))) * 8 +
                      (g & 1) * 4;
        *(bf16x4*)(Kp + koff) = kv;
      } else {
        #pragma unroll
        for (int i = 0; i < 4; ++i) {
          int d = o_lo - 64 + i;
          int jr = n & 31, jb2 = n >> 5;
          int reg = ((jr >> 4) << 2) | (jr & 3);
          int gg = (jr >> 2) & 3;
          int half = d >> 4;
          int lane2 = gg * 16 + (d & 15);
          Vb[(((size_t)bh * 128 + jb2) * 2 + half) * 512 + lane2 * 8 + reg] =
              (__bf16)(v[i] + bias[i]);
        }
      }
    }
  }
  __threadfence();
  grid.sync();

  // ---------------- Phase C: flash attention (64 q/wave) -------------------
  {
    int bh = blk & 7;  // same bh -> same XCD (K/V L2 locality)
    int ks = (blk >> 3) & 3;
    int qt = blk >> 5;  // 0..15
    int qi = qt * 256 + wave * 64 + r;  // lane's queries: qi + 16j, j=0..3
    const __bf16* qbase = Qb + ((size_t)bh * 4096 + qi) * 32 + 8 * g;
    bf16x8 qf[4];
    #pragma unroll
    for (int j = 0; j < 4; ++j) qf[j] = *(const bf16x8*)(qbase + j * 512);
    const __bf16* ktile = Kp + (size_t)bh * 131072;
    const __bf16* vtile = Vb + (size_t)bh * 131072;
    __bf16* kls = (__bf16*)smraw;            // [3][1024]
    __bf16* vls = (__bf16*)(smraw + 6144);   // [3][1024]
    bf16x8 ones;
    #pragma unroll
    for (int i = 0; i < 8; ++i) ones[i] = (__bf16)1.0f;
    f32x4 acc[4][2], accd[4];
    #pragma unroll
    for (int j = 0; j < 4; ++j) {
      acc[j][0] = (f32x4){0.f, 0.f, 0.f, 0.f};
      acc[j][1] = (f32x4){0.f, 0.f, 0.f, 0.f};
      accd[j] = (f32x4){0.f, 0.f, 0.f, 0.f};
    }
    int jb0 = ks * 32;
    // waves 0,1 stage K halves; 2,3 stage V halves. 16B/lane, wave-linear dst.
    auto stage = [&](int buf, int jb) {
      const __bf16* src;
      __bf16* dst;
      if (wave < 2) {
        src = ktile + jb * 1024 + wave * 512 + lane * 8;
        dst = kls + buf * 1024 + wave * 512;
      } else {
        src = vtile + jb * 1024 + (wave - 2) * 512 + lane * 8;
        dst = vls + buf * 1024 + (wave - 2) * 512;
      }
      __builtin_amdgcn_global_load_lds(
          (const __attribute__((address_space(1))) uint32_t*)src,
          (__attribute__((address_space(3))) uint32_t*)dst, 16, 0, 0);
    };
    stage(0, jb0);
    stage(1, jb0 + 1);
    for (int t = 0; t < 32; ++t) {
      // own-wave wait: tile t landed (t+1 may still fly); barrier then
      // guarantees all waves' tile-t pieces landed. Loads span barriers.
      asm volatile("s_waitcnt vmcnt(1)" ::: "memory");
      __builtin_amdgcn_sched_barrier(0);
      __builtin_amdgcn_s_barrier();
      int buf = t % 3;
      bf16x8 kc0 = *(const bf16x8*)(kls + buf * 1024 + lane * 8);
      bf16x8 kc1 = *(const bf16x8*)(kls + buf * 1024 + 512 + lane * 8);
      bf16x8 vc0 = *(const bf16x8*)(vls + buf * 1024 + lane * 8);
      bf16x8 vc1 = *(const bf16x8*)(vls + buf * 1024 + 512 + lane * 8);
      #pragma unroll
      for (int j = 0; j < 4; ++j) {
        f32x4 z = {0.f, 0.f, 0.f, 0.f};
        f32x4 s0 = mfma_16x16x32(kc0, qf[j], z);  // keys 4g+i
        f32x4 s1 = mfma_16x16x32(kc1, qf[j], z);  // keys 16+4g+i
        float p[8];
        #pragma unroll
        for (int i = 0; i < 4; ++i) {
          p[i]     = __builtin_amdgcn_exp2f(s0[i]);
          p[4 + i] = __builtin_amdgcn_exp2f(s1[i]);
        }
        bf16x8 pf;
        #pragma unroll
        for (int i = 0; i < 8; ++i) pf[i] = (__bf16)p[i];
        acc[j][0] = mfma_16x16x32(vc0, pf, acc[j][0]);
        acc[j][1] = mfma_16x16x32(vc1, pf, acc[j][1]);
        accd[j]  = mfma_16x16x32(ones, pf, accd[j]);
      }
      int nt = t + 2;
      stage(nt % 3, jb0 + (nt & 31));  // wrap keeps vmcnt count uniform
    }
    #pragma unroll
    for (int j = 0; j < 4; ++j) {
      size_t base = (size_t)(ks * 8 + bh) * 4096 + qi + 16 * j;
      bf16x4 o0, o1;
      #pragma unroll
      for (int i = 0; i < 4; ++i) {
        o0[i] = (__bf16)acc[j][0][i];
        o1[i] = (__bf16)acc[j][1][i];
      }
      *(bf16x4*)(Op + base * 32 + 4 * g) = o0;
      *(bf16x4*)(Op + base * 32 + 16 + 4 * g) = o1;
      if (g == 0) Lp[base] = accd[j][0];
    }
  }
  __threadfence();
  grid.sync();

  // ---------------- Phase D: combine partials + out projection -------------
  {
    __bf16* ol = (__bf16*)smraw;                      // 4 KB swizzled O tile
    float (*rl)[4] = (float(*)[4])(smraw + 4096);     // [16][4]
    float (*xl)[20] = (float(*)[20])(smraw + 4352);   // [128][20] residual
    int b = blk >> 8;
    int n0 = (blk & 255) * 16;
    if (tid < 64) {
      int t = tid >> 2, hh = tid & 3;
      size_t qidx = (size_t)(b * 4 + hh) * 4096 + n0 + t;
      float l = Lp[qidx] + Lp[qidx + 8 * 4096] + Lp[qidx + 16 * 4096] +
                Lp[qidx + 24 * 4096];
      rl[t][hh] = 1.f / l;
    }
    {
      int c = tid >> 1, hf = tid & 1;
      const float* xs = x + ((size_t)b * 128 + c) * 4096 + n0 + hf * 8;
      f32x4 x0 = *(const f32x4*)xs;
      f32x4 x1 = *(const f32x4*)(xs + 4);
      *(f32x4*)&xl[c][hf * 8] = x0;
      *(f32x4*)&xl[c][hf * 8 + 4] = x1;
    }
    __syncthreads();
    {
      int t = tid >> 4, p8 = (tid & 15) * 8;
      int hh = p8 >> 5;
      size_t base = ((size_t)(b * 4 + hh) * 4096 + n0 + t) * 32 + (p8 & 31);
      float s[8] = {0.f, 0.f, 0.f, 0.f, 0.f, 0.f, 0.f, 0.f};
      #pragma unroll
      for (int ks = 0; ks < 4; ++ks) {
        bf16x8 v = *(const bf16x8*)(Op + base + (size_t)ks * 1048576);
        #pragma unroll
        for (int j = 0; j < 8; ++j) s[j] += (float)v[j];
      }
      float sc = rl[t][hh];
      bf16x8 ob8;
      #pragma unroll
      for (int j = 0; j < 8; ++j) ob8[j] = (__bf16)(s[j] * sc);
      int byte = (t * 256 + p8 * 2) ^ ((t & 7) << 4);
      *(bf16x8*)((char*)ol + byte) = ob8;
    }
    __syncthreads();
    bf16x8 bfr[4];
    #pragma unroll
    for (int ks = 0; ks < 4; ++ks) {
      int byte = (r * 256 + ks * 64 + g * 16) ^ ((r & 7) << 4);
      bfr[ks] = *(const bf16x8*)((char*)ol + byte);
    }
    const bf16x8* wqp = (const bf16x8*)Wq;
    f32x4 acc[2];
    #pragma unroll
    for (int ot = 0; ot < 2; ++ot) {
      acc[ot] = (f32x4){0.f, 0.f, 0.f, 0.f};
      #pragma unroll
      for (int ks = 0; ks < 4; ++ks)
        acc[ot] = mfma_16x16x32(wqp[((wave * 2 + ot) * 4 + ks) * 64 + lane],
                                bfr[ks], acc[ot]);
    }
    int n = n0 + r;
    #pragma unroll
    for (int ot = 0; ot < 2; ++ot) {
      int c0 = wave * 32 + ot * 16 + 4 * g;
      f32x4 bias = *(const f32x4*)(ob + c0);
      f32x4 o = acc[ot];
      #pragma unroll
      for (int i = 0; i < 4; ++i) o[i] += bias[i] + xl[c0 + i][r];
      *(f32x4*)(out + ((size_t)b * 4096 + n) * 128 + c0) = o;
    }
  }
}

extern "C" void kernel_launch(void* const* d_in, const int* in_sizes, int n_in,
                              void* d_out, int out_size, void* d_ws, size_t ws_size,
                              hipStream_t stream) {
  const float* x  = (const float*)d_in[0];
  const float* nw = (const float*)d_in[2];
  const float* nb = (const float*)d_in[3];
  const float* pw = (const float*)d_in[4];
  const float* pb = (const float*)d_in[5];
  const float* ow = (const float*)d_in[6];
  const float* ob = (const float*)d_in[7];
  float* out = (float*)d_out;

  char* ws = (char*)d_ws;
  float* stats = (float*)ws;                       // 1 KB
  __bf16* Qb = (__bf16*)(ws + 1024);               // 2 MB
  __bf16* Kp = (__bf16*)(ws + 1024 + 2097152);     // 2 MB (frag-linear tiles)
  __bf16* Vb = (__bf16*)(ws + 1024 + 4194304);     // 2 MB (frag-linear tiles)
  __bf16* Op = (__bf16*)(ws + 1024 + 6291456);     // 8 MB [4ks][8bh][4096][32]
  float*  Lp = (float*)(ws + 1024 + 14680064);     // 512 KB
  __bf16* Wp = (__bf16*)(ws + 1024 + 15204352);    // 96 KB
  __bf16* Wq = (__bf16*)(ws + 1024 + 15302656);    // 32 KB

  void* args[] = {&x, &nw, &nb, &pw, &pb, &ow, &ob, &out,
                  &stats, &Qb, &Kp, &Vb, &Op, &Lp, &Wp, &Wq};
  hipLaunchCooperativeKernel((void*)mega_kernel, dim3(512), dim3(256),
                             args, 0, stream);
}

// Round 9
// 121.338 us; speedup vs baseline: 3.8312x; 3.8312x over previous
//
#include <hip/hip_runtime.h>
#include <hip/hip_bf16.h>

typedef __bf16 bf16x8 __attribute__((ext_vector_type(8)));
typedef __bf16 bf16x4 __attribute__((ext_vector_type(4)));
typedef float f32x4 __attribute__((ext_vector_type(4)));

// scale = d^-0.5 * log2(e): attention runs in log2 domain (exp2, no max needed:
// GroupNorm'd activations x 0.02-scale weights give |scores| < ~0.5 log2 units)
#define QSCALE (0.17677669529663689f * 1.44269504088896340736f)

__device__ __forceinline__ f32x4 mfma_16x16x32(bf16x8 a, bf16x8 b, f32x4 c) {
  return __builtin_amdgcn_mfma_f32_16x16x32_bf16(a, b, c, 0, 0, 0);
}

// ------- Kernel A: GroupNorm stats (blocks 0..63) + weight pre-pack (64..95)
__global__ __launch_bounds__(256) void prep_kernel(
    const float* __restrict__ x, float* __restrict__ stats,
    const float* __restrict__ pw, const float* __restrict__ ow,
    __bf16* __restrict__ Wp, __bf16* __restrict__ Wq) {
  if (blockIdx.x < 64) {
    int bg = blockIdx.x;
    const f32x4* base = (const f32x4*)(x + (size_t)bg * 16384);
    float s = 0.f, ss = 0.f;
    for (int i = threadIdx.x; i < 4096; i += 256) {
      f32x4 v = base[i];
      s += v[0] + v[1] + v[2] + v[3];
      ss += v[0]*v[0] + v[1]*v[1] + v[2]*v[2] + v[3]*v[3];
    }
    #pragma unroll
    for (int off = 32; off; off >>= 1) {
      s += __shfl_down(s, off);
      ss += __shfl_down(ss, off);
    }
    __shared__ float rs[4], rss[4];
    int wid = threadIdx.x >> 6;
    if ((threadIdx.x & 63) == 0) { rs[wid] = s; rss[wid] = ss; }
    __syncthreads();
    if (threadIdx.x == 0) {
      float S = rs[0] + rs[1] + rs[2] + rs[3];
      float SS = rss[0] + rss[1] + rss[2] + rss[3];
      float mean = S * (1.f / 16384.f);
      float var = SS * (1.f / 16384.f) - mean * mean;
      stats[bg * 2] = mean;
      stats[bg * 2 + 1] = rsqrtf(var + 1e-5f);
    }
    return;
  }
  int idx = (blockIdx.x - 64) * 256 + threadIdx.x;  // 0..8191
  const float* src;
  __bf16* dst;
  if (idx < 6144) {
    int lane = idx & 63, ks = (idx >> 6) & 3;
    int rest = idx >> 8;  // 0..23
    int ot = rest % 6, hh = rest / 6;
    src = pw + (size_t)(hh * 96 + ot * 16 + (lane & 15)) * 128 + ks * 32 +
          8 * (lane >> 4);
    dst = Wp + (size_t)idx * 8;
  } else {
    int j = idx - 6144;  // 0..2047
    int lane = j & 63, ks = (j >> 6) & 3;
    int rest = j >> 8;  // 0..7
    int ot = rest & 1, wv = rest >> 1;
    src = ow + (size_t)(wv * 32 + ot * 16 + (lane & 15)) * 128 + ks * 32 +
          8 * (lane >> 4);
    dst = Wq + (size_t)j * 8;
  }
  f32x4 a = *(const f32x4*)src;
  f32x4 b2 = *(const f32x4*)(src + 4);
  bf16x8 w;
  #pragma unroll
  for (int i = 0; i < 4; ++i) { w[i] = (__bf16)a[i]; w[4 + i] = (__bf16)b2[i]; }
  *(bf16x8*)dst = w;
}

// ---------------- Kernel B: GroupNorm apply + QKV projection (bf16 MFMA) ----
// grid = 2b * 256 chunks of 16 tokens; 4 waves = 4 heads. Weights from Wp.
__global__ __launch_bounds__(256) void qkv_kernel(
    const float* __restrict__ x, const float* __restrict__ stats,
    const float* __restrict__ nw, const float* __restrict__ nb,
    const __bf16* __restrict__ Wp, const float* __restrict__ pb,
    __bf16* __restrict__ Qb, __bf16* __restrict__ Kp, __bf16* __restrict__ Vb) {
  __shared__ __bf16 ht[16 * 128];  // XOR-swizzled [token][c]
  int chunk = blockIdx.x & 255;
  int b = blockIdx.x >> 8;
  int tid = threadIdx.x;
  int n0 = chunk * 16;
  {
    int c = tid >> 1, hf = tid & 1;
    const float* xs = x + ((size_t)b * 128 + c) * 4096 + n0 + hf * 8;
    f32x4 x0 = *(const f32x4*)xs;
    f32x4 x1 = *(const f32x4*)(xs + 4);
    float mean = stats[(b * 32 + (c >> 2)) * 2];
    float rstd = stats[(b * 32 + (c >> 2)) * 2 + 1];
    float wsc = nw[c], bsc = nb[c];
    #pragma unroll
    for (int j = 0; j < 8; ++j) {
      float v = (j < 4) ? x0[j] : x1[j - 4];
      float hv = (v - mean) * rstd * wsc + bsc;
      int tok = hf * 8 + j;
      int byte = (tok * 256 + c * 2) ^ ((tok & 7) << 4);
      *(__bf16*)((char*)ht + byte) = (__bf16)hv;
    }
  }
  int wave = tid >> 6, lane = tid & 63;
  int g = lane >> 4, r = lane & 15;
  int hh = wave;
  bf16x8 wf[6][4];
  const bf16x8* wpp = (const bf16x8*)Wp;
  #pragma unroll
  for (int ot = 0; ot < 6; ++ot)
    #pragma unroll
    for (int ks = 0; ks < 4; ++ks)
      wf[ot][ks] = wpp[((hh * 6 + ot) * 4 + ks) * 64 + lane];
  __syncthreads();
  bf16x8 bfr[4];
  #pragma unroll
  for (int ks = 0; ks < 4; ++ks) {
    int byte = (r * 256 + (ks * 32 + 8 * g) * 2) ^ ((r & 7) << 4);
    bfr[ks] = *(const bf16x8*)((char*)ht + byte);
  }
  f32x4 acc[6];
  #pragma unroll
  for (int ot = 0; ot < 6; ++ot) acc[ot] = (f32x4){0.f, 0.f, 0.f, 0.f};
  #pragma unroll
  for (int ks = 0; ks < 4; ++ks)
    #pragma unroll
    for (int ot = 0; ot < 6; ++ot)
      acc[ot] = mfma_16x16x32(wf[ot][ks], bfr[ks], acc[ot]);
  int bh = b * 4 + hh;
  int n = n0 + r;
  #pragma unroll
  for (int ot = 0; ot < 6; ++ot) {
    int o_lo = ot * 16 + 4 * g;
    f32x4 bias = *(const f32x4*)(pb + hh * 96 + o_lo);
    f32x4 v = acc[ot];
    if (ot < 2) {
      bf16x4 qv;
      #pragma unroll
      for (int i = 0; i < 4; ++i) qv[i] = (__bf16)((v[i] + bias[i]) * QSCALE);
      *(bf16x4*)(Qb + ((size_t)bh * 4096 + n) * 32 + o_lo) = qv;
    } else if (ot < 4) {
      // K fragment-linear: tile jb=n>>5, half=(n>>4)&1, within-half chunk
      bf16x4 kv;
      #pragma unroll
      for (int i = 0; i < 4; ++i) kv[i] = (__bf16)(v[i] + bias[i]);
      size_t koff = ((size_t)(bh * 128 + (n >> 5))) * 1024 +
                    (size_t)((n >> 4) & 1) * 512 +
                    ((n & 15) + 16 * ((ot - 2) * 2 + (g >> 1))) * 8 +
                    (g & 1) * 4;
      *(bf16x4*)(Kp + koff) = kv;
    } else {
      #pragma unroll
      for (int i = 0; i < 4; ++i) {
        int d = o_lo - 64 + i;
        int jr = n & 31, jb2 = n >> 5;
        int reg = ((jr >> 4) << 2) | (jr & 3);
        int gg = (jr >> 2) & 3;
        int half = d >> 4;
        int lane2 = gg * 16 + (d & 15);
        Vb[(((size_t)bh * 128 + jb2) * 2 + half) * 512 + lane2 * 8 + reg] =
            (__bf16)(v[i] + bias[i]);
      }
    }
  }
}

// ---------------- Kernel C: flash attention, 64 q/wave, pipelined LDS K/V ---
// Triple-buffered global_load_lds, counted vmcnt(1) before each raw s_barrier
// (T3/T4). grid 512 = 8bh x 4ks x 16qt: half the barrier-waves and half the
// K/V L2 re-reads of the 32q version; 4 independent q-chains of ILP per wave.
__global__ __launch_bounds__(256) void attn_kernel(
    const __bf16* __restrict__ Qb, const __bf16* __restrict__ Kp,
    const __bf16* __restrict__ Vb, __bf16* __restrict__ Op,
    float* __restrict__ Lp) {
  __shared__ __bf16 kls[3][1024];
  __shared__ __bf16 vls[3][1024];
  int bh = blockIdx.x & 7;  // same bh -> same XCD (K/V L2 locality)
  int ks = (blockIdx.x >> 3) & 3;
  int qt = blockIdx.x >> 5;  // 0..15
  int wave = threadIdx.x >> 6;
  int lane = threadIdx.x & 63;
  int g = lane >> 4, r = lane & 15;
  int qi = qt * 256 + wave * 64 + r;  // lane's queries: qi + 16j, j=0..3
  const __bf16* qbase = Qb + ((size_t)bh * 4096 + qi) * 32 + 8 * g;
  bf16x8 qf[4];
  #pragma unroll
  for (int j = 0; j < 4; ++j) qf[j] = *(const bf16x8*)(qbase + j * 512);
  const __bf16* ktile = Kp + (size_t)bh * 131072;
  const __bf16* vtile = Vb + (size_t)bh * 131072;
  bf16x8 ones;
  #pragma unroll
  for (int i = 0; i < 8; ++i) ones[i] = (__bf16)1.0f;
  f32x4 acc[4][2], accd[4];
  #pragma unroll
  for (int j = 0; j < 4; ++j) {
    acc[j][0] = (f32x4){0.f, 0.f, 0.f, 0.f};
    acc[j][1] = (f32x4){0.f, 0.f, 0.f, 0.f};
    accd[j] = (f32x4){0.f, 0.f, 0.f, 0.f};
  }
  int jb0 = ks * 32;
  // waves 0,1 stage K halves; 2,3 stage V halves. 16B/lane, wave-linear dst.
  auto stage = [&](int buf, int jb) {
    const __bf16* src;
    __bf16* dst;
    if (wave < 2) {
      src = ktile + jb * 1024 + wave * 512 + lane * 8;
      dst = &kls[buf][wave * 512];
    } else {
      src = vtile + jb * 1024 + (wave - 2) * 512 + lane * 8;
      dst = &vls[buf][(wave - 2) * 512];
    }
    __builtin_amdgcn_global_load_lds(
        (const __attribute__((address_space(1))) uint32_t*)src,
        (__attribute__((address_space(3))) uint32_t*)dst, 16, 0, 0);
  };
  stage(0, jb0);
  stage(1, jb0 + 1);
  for (int t = 0; t < 32; ++t) {
    // own-wave wait: tile t landed (t+1 may still fly); barrier then
    // guarantees all waves' tile-t pieces landed. Loads span barriers.
    asm volatile("s_waitcnt vmcnt(1)" ::: "memory");
    __builtin_amdgcn_sched_barrier(0);
    __builtin_amdgcn_s_barrier();
    int buf = t % 3;
    bf16x8 kc0 = *(const bf16x8*)&kls[buf][lane * 8];
    bf16x8 kc1 = *(const bf16x8*)&kls[buf][512 + lane * 8];
    bf16x8 vc0 = *(const bf16x8*)&vls[buf][lane * 8];
    bf16x8 vc1 = *(const bf16x8*)&vls[buf][512 + lane * 8];
    #pragma unroll
    for (int j = 0; j < 4; ++j) {
      f32x4 z = {0.f, 0.f, 0.f, 0.f};
      f32x4 s0 = mfma_16x16x32(kc0, qf[j], z);  // keys 4g+i
      f32x4 s1 = mfma_16x16x32(kc1, qf[j], z);  // keys 16+4g+i
      float p[8];
      #pragma unroll
      for (int i = 0; i < 4; ++i) {
        p[i]     = __builtin_amdgcn_exp2f(s0[i]);
        p[4 + i] = __builtin_amdgcn_exp2f(s1[i]);
      }
      bf16x8 pf;
      #pragma unroll
      for (int i = 0; i < 8; ++i) pf[i] = (__bf16)p[i];
      acc[j][0] = mfma_16x16x32(vc0, pf, acc[j][0]);
      acc[j][1] = mfma_16x16x32(vc1, pf, acc[j][1]);
      accd[j]  = mfma_16x16x32(ones, pf, accd[j]);
    }
    int nt = t + 2;
    stage(nt % 3, jb0 + (nt & 31));  // wrap keeps vmcnt count uniform
  }
  #pragma unroll
  for (int j = 0; j < 4; ++j) {
    size_t base = (size_t)(ks * 8 + bh) * 4096 + qi + 16 * j;
    bf16x4 o0, o1;
    #pragma unroll
    for (int i = 0; i < 4; ++i) {
      o0[i] = (__bf16)acc[j][0][i];
      o1[i] = (__bf16)acc[j][1][i];
    }
    *(bf16x4*)(Op + base * 32 + 4 * g) = o0;
    *(bf16x4*)(Op + base * 32 + 16 + 4 * g) = o1;
    if (g == 0) Lp[base] = accd[j][0];
  }
}

// ---------------- Kernel D: combine partials + out projection (MFMA) --------
__global__ __launch_bounds__(256) void proj_out_kernel(
    const __bf16* __restrict__ Op, const float* __restrict__ Lp,
    const __bf16* __restrict__ Wq, const float* __restrict__ ob,
    const float* __restrict__ x, float* __restrict__ out) {
  __shared__ __bf16 ol[2048];    // XOR-swizzled combined O [tok16][d128]
  __shared__ float rl[16][4];
  __shared__ float xl[128][20];  // residual tile [c][tok16], pad 20
  int b = blockIdx.x >> 8;
  int n0 = (blockIdx.x & 255) * 16;
  int tid = threadIdx.x;
  if (tid < 64) {
    int t = tid >> 2, hh = tid & 3;
    size_t qidx = (size_t)(b * 4 + hh) * 4096 + n0 + t;
    float l = Lp[qidx] + Lp[qidx + 8 * 4096] + Lp[qidx + 16 * 4096] +
              Lp[qidx + 24 * 4096];
    rl[t][hh] = 1.f / l;
  }
  {  // stage residual x tile: c = tid>>1, token-half = tid&1
    int c = tid >> 1, hf = tid & 1;
    const float* xs = x + ((size_t)b * 128 + c) * 4096 + n0 + hf * 8;
    f32x4 x0 = *(const f32x4*)xs;
    f32x4 x1 = *(const f32x4*)(xs + 4);
    *(f32x4*)&xl[c][hf * 8] = x0;
    *(f32x4*)&xl[c][hf * 8 + 4] = x1;
  }
  __syncthreads();
  {
    int t = tid >> 4, p8 = (tid & 15) * 8;
    int hh = p8 >> 5;
    size_t base = ((size_t)(b * 4 + hh) * 4096 + n0 + t) * 32 + (p8 & 31);
    float s[8] = {0.f, 0.f, 0.f, 0.f, 0.f, 0.f, 0.f, 0.f};
    #pragma unroll
    for (int ks = 0; ks < 4; ++ks) {
      bf16x8 v = *(const bf16x8*)(Op + base + (size_t)ks * 1048576);
      #pragma unroll
      for (int j = 0; j < 8; ++j) s[j] += (float)v[j];
    }
    float sc = rl[t][hh];
    bf16x8 ob8;
    #pragma unroll
    for (int j = 0; j < 8; ++j) ob8[j] = (__bf16)(s[j] * sc);
    int byte = (t * 256 + p8 * 2) ^ ((t & 7) << 4);
    *(bf16x8*)((char*)ol + byte) = ob8;
  }
  __syncthreads();
  int wave = tid >> 6, lane = tid & 63;
  int g = lane >> 4, r = lane & 15;
  bf16x8 bfr[4];
  #pragma unroll
  for (int ks = 0; ks < 4; ++ks) {
    int byte = (r * 256 + ks * 64 + g * 16) ^ ((r & 7) << 4);
    bfr[ks] = *(const bf16x8*)((char*)ol + byte);
  }
  const bf16x8* wqp = (const bf16x8*)Wq;
  f32x4 acc[2];
  #pragma unroll
  for (int ot = 0; ot < 2; ++ot) {
    acc[ot] = (f32x4){0.f, 0.f, 0.f, 0.f};
    #pragma unroll
    for (int ks = 0; ks < 4; ++ks)
      acc[ot] = mfma_16x16x32(wqp[((wave * 2 + ot) * 4 + ks) * 64 + lane],
                              bfr[ks], acc[ot]);
  }
  int n = n0 + r;
  #pragma unroll
  for (int ot = 0; ot < 2; ++ot) {
    int c0 = wave * 32 + ot * 16 + 4 * g;
    f32x4 bias = *(const f32x4*)(ob + c0);
    f32x4 o = acc[ot];
    #pragma unroll
    for (int i = 0; i < 4; ++i) o[i] += bias[i] + xl[c0 + i][r];
    *(f32x4*)(out + ((size_t)b * 4096 + n) * 128 + c0) = o;
  }
}

extern "C" void kernel_launch(void* const* d_in, const int* in_sizes, int n_in,
                              void* d_out, int out_size, void* d_ws, size_t ws_size,
                              hipStream_t stream) {
  const float* x  = (const float*)d_in[0];
  const float* nw = (const float*)d_in[2];
  const float* nb = (const float*)d_in[3];
  const float* pw = (const float*)d_in[4];
  const float* pb = (const float*)d_in[5];
  const float* ow = (const float*)d_in[6];
  const float* ob = (const float*)d_in[7];
  float* out = (float*)d_out;

  char* ws = (char*)d_ws;
  float* stats = (float*)ws;                       // 1 KB
  __bf16* Qb = (__bf16*)(ws + 1024);               // 2 MB
  __bf16* Kp = (__bf16*)(ws + 1024 + 2097152);     // 2 MB (frag-linear tiles)
  __bf16* Vb = (__bf16*)(ws + 1024 + 4194304);     // 2 MB (frag-linear tiles)
  __bf16* Op = (__bf16*)(ws + 1024 + 6291456);     // 8 MB [4ks][8bh][4096][32]
  float*  Lp = (float*)(ws + 1024 + 14680064);     // 512 KB
  __bf16* Wp = (__bf16*)(ws + 1024 + 15204352);    // 96 KB
  __bf16* Wq = (__bf16*)(ws + 1024 + 15302656);    // 32 KB

  prep_kernel<<<96, 256, 0, stream>>>(x, stats, pw, ow, Wp, Wq);
  qkv_kernel<<<512, 256, 0, stream>>>(x, stats, nw, nb, Wp, pb, Qb, Kp, Vb);
  attn_kernel<<<512, 256, 0, stream>>>(Qb, Kp, Vb, Op, Lp);
  proj_out_kernel<<<512, 256, 0, stream>>>(Op, Lp, Wq, ob, x, out);
}

// Round 11
// 120.129 us; speedup vs baseline: 3.8698x; 1.0101x over previous
//
#include <hip/hip_runtime.h>
#include <hip/hip_bf16.h>

typedef __bf16 bf16x8 __attribute__((ext_vector_type(8)));
typedef __bf16 bf16x4 __attribute__((ext_vector_type(4)));
typedef float f32x4 __attribute__((ext_vector_type(4)));

// scale = d^-0.5 * log2(e): attention runs in log2 domain (exp2, no max needed:
// GroupNorm'd activations x 0.02-scale weights give |scores| < ~0.5 log2 units)
#define QSCALE (0.17677669529663689f * 1.44269504088896340736f)

__device__ __forceinline__ f32x4 mfma_16x16x32(bf16x8 a, bf16x8 b, f32x4 c) {
  return __builtin_amdgcn_mfma_f32_16x16x32_bf16(a, b, c, 0, 0, 0);
}

// ------- Kernel A: GroupNorm stats (blocks 0..63) + weight pre-pack (64..95)
__global__ __launch_bounds__(256) void prep_kernel(
    const float* __restrict__ x, float* __restrict__ stats,
    const float* __restrict__ pw, const float* __restrict__ ow,
    __bf16* __restrict__ Wp, __bf16* __restrict__ Wq) {
  if (blockIdx.x < 64) {
    int bg = blockIdx.x;
    const f32x4* base = (const f32x4*)(x + (size_t)bg * 16384);
    float s = 0.f, ss = 0.f;
    for (int i = threadIdx.x; i < 4096; i += 256) {
      f32x4 v = base[i];
      s += v[0] + v[1] + v[2] + v[3];
      ss += v[0]*v[0] + v[1]*v[1] + v[2]*v[2] + v[3]*v[3];
    }
    #pragma unroll
    for (int off = 32; off; off >>= 1) {
      s += __shfl_down(s, off);
      ss += __shfl_down(ss, off);
    }
    __shared__ float rs[4], rss[4];
    int wid = threadIdx.x >> 6;
    if ((threadIdx.x & 63) == 0) { rs[wid] = s; rss[wid] = ss; }
    __syncthreads();
    if (threadIdx.x == 0) {
      float S = rs[0] + rs[1] + rs[2] + rs[3];
      float SS = rss[0] + rss[1] + rss[2] + rss[3];
      float mean = S * (1.f / 16384.f);
      float var = SS * (1.f / 16384.f) - mean * mean;
      stats[bg * 2] = mean;
      stats[bg * 2 + 1] = rsqrtf(var + 1e-5f);
    }
    return;
  }
  int idx = (blockIdx.x - 64) * 256 + threadIdx.x;  // 0..8191
  const float* src;
  __bf16* dst;
  if (idx < 6144) {
    int lane = idx & 63, ks = (idx >> 6) & 3;
    int rest = idx >> 8;  // 0..23
    int ot = rest % 6, hh = rest / 6;
    src = pw + (size_t)(hh * 96 + ot * 16 + (lane & 15)) * 128 + ks * 32 +
          8 * (lane >> 4);
    dst = Wp + (size_t)idx * 8;
  } else {
    int j = idx - 6144;  // 0..2047
    int lane = j & 63, ks = (j >> 6) & 3;
    int rest = j >> 8;  // 0..7
    int ot = rest & 1, wv = rest >> 1;
    src = ow + (size_t)(wv * 32 + ot * 16 + (lane & 15)) * 128 + ks * 32 +
          8 * (lane >> 4);
    dst = Wq + (size_t)j * 8;
  }
  f32x4 a = *(const f32x4*)src;
  f32x4 b2 = *(const f32x4*)(src + 4);
  bf16x8 w;
  #pragma unroll
  for (int i = 0; i < 4; ++i) { w[i] = (__bf16)a[i]; w[4 + i] = (__bf16)b2[i]; }
  *(bf16x8*)dst = w;
}

// ---------------- Kernel B: GroupNorm apply + QKV projection (bf16 MFMA) ----
// grid = 2b * 256 chunks of 16 tokens; 4 waves = 4 heads. Weights from Wp.
__global__ __launch_bounds__(256) void qkv_kernel(
    const float* __restrict__ x, const float* __restrict__ stats,
    const float* __restrict__ nw, const float* __restrict__ nb,
    const __bf16* __restrict__ Wp, const float* __restrict__ pb,
    __bf16* __restrict__ Qb, __bf16* __restrict__ Kp, __bf16* __restrict__ Vb) {
  __shared__ __bf16 ht[16 * 128];  // XOR-swizzled [token][c]
  int chunk = blockIdx.x & 255;
  int b = blockIdx.x >> 8;
  int tid = threadIdx.x;
  int n0 = chunk * 16;
  {
    int c = tid >> 1, hf = tid & 1;
    const float* xs = x + ((size_t)b * 128 + c) * 4096 + n0 + hf * 8;
    f32x4 x0 = *(const f32x4*)xs;
    f32x4 x1 = *(const f32x4*)(xs + 4);
    float mean = stats[(b * 32 + (c >> 2)) * 2];
    float rstd = stats[(b * 32 + (c >> 2)) * 2 + 1];
    float wsc = nw[c], bsc = nb[c];
    #pragma unroll
    for (int j = 0; j < 8; ++j) {
      float v = (j < 4) ? x0[j] : x1[j - 4];
      float hv = (v - mean) * rstd * wsc + bsc;
      int tok = hf * 8 + j;
      int byte = (tok * 256 + c * 2) ^ ((tok & 7) << 4);
      *(__bf16*)((char*)ht + byte) = (__bf16)hv;
    }
  }
  int wave = tid >> 6, lane = tid & 63;
  int g = lane >> 4, r = lane & 15;
  int hh = wave;
  bf16x8 wf[6][4];
  const bf16x8* wpp = (const bf16x8*)Wp;
  #pragma unroll
  for (int ot = 0; ot < 6; ++ot)
    #pragma unroll
    for (int ks = 0; ks < 4; ++ks)
      wf[ot][ks] = wpp[((hh * 6 + ot) * 4 + ks) * 64 + lane];
  __syncthreads();
  bf16x8 bfr[4];
  #pragma unroll
  for (int ks = 0; ks < 4; ++ks) {
    int byte = (r * 256 + (ks * 32 + 8 * g) * 2) ^ ((r & 7) << 4);
    bfr[ks] = *(const bf16x8*)((char*)ht + byte);
  }
  f32x4 acc[6];
  #pragma unroll
  for (int ot = 0; ot < 6; ++ot) acc[ot] = (f32x4){0.f, 0.f, 0.f, 0.f};
  #pragma unroll
  for (int ks = 0; ks < 4; ++ks)
    #pragma unroll
    for (int ot = 0; ot < 6; ++ot)
      acc[ot] = mfma_16x16x32(wf[ot][ks], bfr[ks], acc[ot]);
  int bh = b * 4 + hh;
  int n = n0 + r;
  #pragma unroll
  for (int ot = 0; ot < 6; ++ot) {
    int o_lo = ot * 16 + 4 * g;
    f32x4 bias = *(const f32x4*)(pb + hh * 96 + o_lo);
    f32x4 v = acc[ot];
    if (ot < 2) {
      bf16x4 qv;
      #pragma unroll
      for (int i = 0; i < 4; ++i) qv[i] = (__bf16)((v[i] + bias[i]) * QSCALE);
      *(bf16x4*)(Qb + ((size_t)bh * 4096 + n) * 32 + o_lo) = qv;
    } else if (ot < 4) {
      // K fragment-linear: tile jb=n>>5, half=(n>>4)&1, within-half chunk
      bf16x4 kv;
      #pragma unroll
      for (int i = 0; i < 4; ++i) kv[i] = (__bf16)(v[i] + bias[i]);
      size_t koff = ((size_t)(bh * 128 + (n >> 5))) * 1024 +
                    (size_t)((n >> 4) & 1) * 512 +
                    ((n & 15) + 16 * ((ot - 2) * 2 + (g >> 1))) * 8 +
                    (g & 1) * 4;
      *(bf16x4*)(Kp + koff) = kv;
    } else {
      #pragma unroll
      for (int i = 0; i < 4; ++i) {
        int d = o_lo - 64 + i;
        int jr = n & 31, jb2 = n >> 5;
        int reg = ((jr >> 4) << 2) | (jr & 3);
        int gg = (jr >> 2) & 3;
        int half = d >> 4;
        int lane2 = gg * 16 + (d & 15);
        Vb[(((size_t)bh * 128 + jb2) * 2 + half) * 512 + lane2 * 8 + reg] =
            (__bf16)(v[i] + bias[i]);
      }
    }
  }
}

// ---------------- Kernel C: flash attention, 32 q/wave, key-split x2 --------
// Triple-buffered global_load_lds, counted vmcnt(1) before each raw s_barrier
// (T3/T4). grid 512 = 8bh x 2ks x 32qt, 2 blocks/CU. 64-tile loop per block;
// half the Op/Lp partial round-trip of the x4 split.
__global__ __launch_bounds__(256) void attn_kernel(
    const __bf16* __restrict__ Qb, const __bf16* __restrict__ Kp,
    const __bf16* __restrict__ Vb, __bf16* __restrict__ Op,
    float* __restrict__ Lp) {
  __shared__ __bf16 kls[3][1024];
  __shared__ __bf16 vls[3][1024];
  int bh = blockIdx.x & 7;  // same bh -> same XCD (K/V L2 locality)
  int ks = (blockIdx.x >> 3) & 1;
  int qt = blockIdx.x >> 4;  // 0..31
  int wave = threadIdx.x >> 6;
  int lane = threadIdx.x & 63;
  int g = lane >> 4, r = lane & 15;
  int qi = qt * 128 + wave * 32 + r;  // this lane's two queries: qi, qi+16
  bf16x8 qf0 = *(const bf16x8*)(Qb + ((size_t)bh * 4096 + qi) * 32 + 8 * g);
  bf16x8 qf1 = *(const bf16x8*)(Qb + ((size_t)bh * 4096 + qi + 16) * 32 + 8 * g);
  const __bf16* ktile = Kp + (size_t)bh * 131072;
  const __bf16* vtile = Vb + (size_t)bh * 131072;
  bf16x8 ones;
  #pragma unroll
  for (int i = 0; i < 8; ++i) ones[i] = (__bf16)1.0f;
  f32x4 acc00 = {0.f,0.f,0.f,0.f}, acc01 = {0.f,0.f,0.f,0.f};
  f32x4 acc10 = {0.f,0.f,0.f,0.f}, acc11 = {0.f,0.f,0.f,0.f};
  f32x4 accd0 = {0.f,0.f,0.f,0.f}, accd1 = {0.f,0.f,0.f,0.f};
  int jb0 = ks * 64;
  // waves 0,1 stage K halves; 2,3 stage V halves. 16B/lane, wave-linear dst.
  auto stage = [&](int buf, int jb) {
    const __bf16* src;
    __bf16* dst;
    if (wave < 2) {
      src = ktile + jb * 1024 + wave * 512 + lane * 8;
      dst = &kls[buf][wave * 512];
    } else {
      src = vtile + jb * 1024 + (wave - 2) * 512 + lane * 8;
      dst = &vls[buf][(wave - 2) * 512];
    }
    __builtin_amdgcn_global_load_lds(
        (const __attribute__((address_space(1))) uint32_t*)src,
        (__attribute__((address_space(3))) uint32_t*)dst, 16, 0, 0);
  };
  stage(0, jb0);
  stage(1, jb0 + 1);
  for (int t = 0; t < 64; ++t) {
    // own-wave wait: tile t landed (t+1 may still fly); barrier then
    // guarantees all waves' tile-t pieces landed. Loads span barriers.
    asm volatile("s_waitcnt vmcnt(1)" ::: "memory");
    __builtin_amdgcn_sched_barrier(0);
    __builtin_amdgcn_s_barrier();
    int buf = t % 3;
    bf16x8 kc0 = *(const bf16x8*)&kls[buf][lane * 8];
    bf16x8 kc1 = *(const bf16x8*)&kls[buf][512 + lane * 8];
    bf16x8 vc0 = *(const bf16x8*)&vls[buf][lane * 8];
    bf16x8 vc1 = *(const bf16x8*)&vls[buf][512 + lane * 8];
    f32x4 z = {0.f, 0.f, 0.f, 0.f};
    f32x4 s00 = mfma_16x16x32(kc0, qf0, z);  // keys 4g+i,       queries qi+r
    f32x4 s01 = mfma_16x16x32(kc1, qf0, z);  // keys 16+4g+i
    f32x4 s10 = mfma_16x16x32(kc0, qf1, z);  // queries qi+16+r
    f32x4 s11 = mfma_16x16x32(kc1, qf1, z);
    float p0[8], p1[8];
    #pragma unroll
    for (int i = 0; i < 4; ++i) {
      p0[i]     = __builtin_amdgcn_exp2f(s00[i]);
      p0[4 + i] = __builtin_amdgcn_exp2f(s01[i]);
      p1[i]     = __builtin_amdgcn_exp2f(s10[i]);
      p1[4 + i] = __builtin_amdgcn_exp2f(s11[i]);
    }
    bf16x8 pf0, pf1;
    #pragma unroll
    for (int i = 0; i < 8; ++i) { pf0[i] = (__bf16)p0[i]; pf1[i] = (__bf16)p1[i]; }
    acc00 = mfma_16x16x32(vc0, pf0, acc00);   // O^T[d 4g..][q]
    acc01 = mfma_16x16x32(vc1, pf0, acc01);   // d 16+4g..
    acc10 = mfma_16x16x32(vc0, pf1, acc10);
    acc11 = mfma_16x16x32(vc1, pf1, acc11);
    accd0 = mfma_16x16x32(ones, pf0, accd0);  // L partial (reg 0)
    accd1 = mfma_16x16x32(ones, pf1, accd1);
    int nt = t + 2;
    stage(nt % 3, jb0 + (nt & 63));  // wrap keeps vmcnt count uniform
  }
  size_t base = (size_t)(ks * 8 + bh) * 4096 + qi;
  bf16x4 o00, o01, o10, o11;
  #pragma unroll
  for (int i = 0; i < 4; ++i) {
    o00[i] = (__bf16)acc00[i]; o01[i] = (__bf16)acc01[i];
    o10[i] = (__bf16)acc10[i]; o11[i] = (__bf16)acc11[i];
  }
  *(bf16x4*)(Op + base * 32 + 4 * g) = o00;
  *(bf16x4*)(Op + base * 32 + 16 + 4 * g) = o01;
  *(bf16x4*)(Op + (base + 16) * 32 + 4 * g) = o10;
  *(bf16x4*)(Op + (base + 16) * 32 + 16 + 4 * g) = o11;
  if (g == 0) { Lp[base] = accd0[0]; Lp[base + 16] = accd1[0]; }
}

// ---------------- Kernel D: combine 2 partials + out projection (MFMA) ------
__global__ __launch_bounds__(256) void proj_out_kernel(
    const __bf16* __restrict__ Op, const float* __restrict__ Lp,
    const __bf16* __restrict__ Wq, const float* __restrict__ ob,
    const float* __restrict__ x, float* __restrict__ out) {
  __shared__ __bf16 ol[2048];    // XOR-swizzled combined O [tok16][d128]
  __shared__ float rl[16][4];
  __shared__ float xl[128][20];  // residual tile [c][tok16], pad 20
  int b = blockIdx.x >> 8;
  int n0 = (blockIdx.x & 255) * 16;
  int tid = threadIdx.x;
  if (tid < 64) {
    int t = tid >> 2, hh = tid & 3;
    size_t qidx = (size_t)(b * 4 + hh) * 4096 + n0 + t;
    float l = Lp[qidx] + Lp[qidx + 8 * 4096];
    rl[t][hh] = 1.f / l;
  }
  {  // stage residual x tile: c = tid>>1, token-half = tid&1
    int c = tid >> 1, hf = tid & 1;
    const float* xs = x + ((size_t)b * 128 + c) * 4096 + n0 + hf * 8;
    f32x4 x0 = *(const f32x4*)xs;
    f32x4 x1 = *(const f32x4*)(xs + 4);
    *(f32x4*)&xl[c][hf * 8] = x0;
    *(f32x4*)&xl[c][hf * 8 + 4] = x1;
  }
  __syncthreads();
  {
    int t = tid >> 4, p8 = (tid & 15) * 8;
    int hh = p8 >> 5;
    size_t base = ((size_t)(b * 4 + hh) * 4096 + n0 + t) * 32 + (p8 & 31);
    float s[8] = {0.f, 0.f, 0.f, 0.f, 0.f, 0.f, 0.f, 0.f};
    #pragma unroll
    for (int ks = 0; ks < 2; ++ks) {
      bf16x8 v = *(const bf16x8*)(Op + base + (size_t)ks * 1048576);
      #pragma unroll
      for (int j = 0; j < 8; ++j) s[j] += (float)v[j];
    }
    float sc = rl[t][hh];
    bf16x8 ob8;
    #pragma unroll
    for (int j = 0; j < 8; ++j) ob8[j] = (__bf16)(s[j] * sc);
    int byte = (t * 256 + p8 * 2) ^ ((t & 7) << 4);
    *(bf16x8*)((char*)ol + byte) = ob8;
  }
  __syncthreads();
  int wave = tid >> 6, lane = tid & 63;
  int g = lane >> 4, r = lane & 15;
  bf16x8 bfr[4];
  #pragma unroll
  for (int ks = 0; ks < 4; ++ks) {
    int byte = (r * 256 + ks * 64 + g * 16) ^ ((r & 7) << 4);
    bfr[ks] = *(const bf16x8*)((char*)ol + byte);
  }
  const bf16x8* wqp = (const bf16x8*)Wq;
  f32x4 acc[2];
  #pragma unroll
  for (int ot = 0; ot < 2; ++ot) {
    acc[ot] = (f32x4){0.f, 0.f, 0.f, 0.f};
    #pragma unroll
    for (int ks = 0; ks < 4; ++ks)
      acc[ot] = mfma_16x16x32(wqp[((wave * 2 + ot) * 4 + ks) * 64 + lane],
                              bfr[ks], acc[ot]);
  }
  int n = n0 + r;
  #pragma unroll
  for (int ot = 0; ot < 2; ++ot) {
    int c0 = wave * 32 + ot * 16 + 4 * g;
    f32x4 bias = *(const f32x4*)(ob + c0);
    f32x4 o = acc[ot];
    #pragma unroll
    for (int i = 0; i < 4; ++i) o[i] += bias[i] + xl[c0 + i][r];
    *(f32x4*)(out + ((size_t)b * 4096 + n) * 128 + c0) = o;
  }
}

extern "C" void kernel_launch(void* const* d_in, const int* in_sizes, int n_in,
                              void* d_out, int out_size, void* d_ws, size_t ws_size,
                              hipStream_t stream) {
  const float* x  = (const float*)d_in[0];
  const float* nw = (const float*)d_in[2];
  const float* nb = (const float*)d_in[3];
  const float* pw = (const float*)d_in[4];
  const float* pb = (const float*)d_in[5];
  const float* ow = (const float*)d_in[6];
  const float* ob = (const float*)d_in[7];
  float* out = (float*)d_out;

  char* ws = (char*)d_ws;
  float* stats = (float*)ws;                       // 1 KB
  __bf16* Qb = (__bf16*)(ws + 1024);               // 2 MB
  __bf16* Kp = (__bf16*)(ws + 1024 + 2097152);     // 2 MB (frag-linear tiles)
  __bf16* Vb = (__bf16*)(ws + 1024 + 4194304);     // 2 MB (frag-linear tiles)
  __bf16* Op = (__bf16*)(ws + 1024 + 6291456);     // 4 MB [2ks][8bh][4096][32]
  float*  Lp = (float*)(ws + 1024 + 14680064);     // 256 KB (offset kept from R7)
  __bf16* Wp = (__bf16*)(ws + 1024 + 15204352);    // 96 KB
  __bf16* Wq = (__bf16*)(ws + 1024 + 15302656);    // 32 KB

  prep_kernel<<<96, 256, 0, stream>>>(x, stats, pw, ow, Wp, Wq);
  qkv_kernel<<<512, 256, 0, stream>>>(x, stats, nw, nb, Wp, pb, Qb, Kp, Vb);
  attn_kernel<<<512, 256, 0, stream>>>(Qb, Kp, Vb, Op, Lp);
  proj_out_kernel<<<512, 256, 0, stream>>>(Op, Lp, Wq, ob, x, out);
}